// Round 2
// baseline (2268.877 us; speedup 1.0000x reference)
//
#include <hip/hip_runtime.h>

#define NPTS 4096
#define NBATCH 8

__device__ __forceinline__ unsigned fenc(float f) {
  unsigned u = __float_as_uint(f);
  return (u & 0x80000000u) ? ~u : (u | 0x80000000u);
}
__device__ __forceinline__ float fdec(unsigned e) {
  unsigned u = (e & 0x80000000u) ? (e ^ 0x80000000u) : ~e;
  return __uint_as_float(u);
}
__device__ __forceinline__ float dot4(float4 a, float4 b) {
  return a.x * b.x + a.y * b.y + a.z * b.z + a.w * b.w;
}

// ---------------- Kernel 1: exact 16-NN + covariance features ----------------
// thread-per-query; batch coords staged in LDS; per-thread sorted-16 list in
// LDS laid out [pos][tid] (bank = tid%32, 2 lanes/bank = conflict-free).
__global__ __launch_bounds__(128)
void k_knn(const float* __restrict__ pts, int* __restrict__ idxo,
           float* __restrict__ x0) {
  __shared__ float sx[NPTS], sy[NPTS], sz[NPTS];       // 48 KB
  __shared__ float sd[16][128];                        // 8 KB
  __shared__ unsigned short si[16][128];               // 4 KB

  const int nch = NPTS / 128;
  const int b = blockIdx.x / nch;
  const int ch = blockIdx.x % nch;
  const float* pb = pts + (size_t)b * NPTS * 3;
  for (int i = threadIdx.x; i < NPTS; i += 128) {
    sx[i] = pb[3 * i];
    sy[i] = pb[3 * i + 1];
    sz[i] = pb[3 * i + 2];
  }
  __syncthreads();

  const int t = threadIdx.x;
  const int q = ch * 128 + t;
  const float qx = sx[q], qy = sy[q], qz = sz[q];
  const float qs = qx * qx + qy * qy + qz * qz;

#pragma unroll
  for (int j = 0; j < 16; j++) { sd[j][t] = 3.0e38f; si[j][t] = 0; }
  float worst = 3.0e38f;

  for (int i = 0; i < NPTS; i++) {
    float cx = sx[i], cy = sy[i], cz = sz[i];
    float sqc = cx * cx + cy * cy + cz * cz;
    float dot = qx * cx + qy * cy + qz * cz;
    float d = qs + sqc - 2.0f * dot;   // same expansion as reference
    if (d < worst) {                   // strict <: ties keep earlier index
      int j = 15;
      while (j > 0 && sd[j - 1][t] > d) {
        sd[j][t] = sd[j - 1][t];
        si[j][t] = si[j - 1][t];
        --j;
      }
      sd[j][t] = d;
      si[j][t] = (unsigned short)i;
      worst = sd[15][t];
    }
  }

  // covariance of mean-centered neighbors
  float nx[16], ny[16], nz[16];
  float mx = 0.f, my = 0.f, mz = 0.f;
#pragma unroll
  for (int k = 0; k < 16; k++) {
    int j = si[k][t];
    nx[k] = sx[j]; ny[k] = sy[j]; nz[k] = sz[j];
    mx += nx[k]; my += ny[k]; mz += nz[k];
  }
  mx *= 0.0625f; my *= 0.0625f; mz *= 0.0625f;
  float c00 = 0, c01 = 0, c02 = 0, c11 = 0, c12 = 0, c22 = 0;
#pragma unroll
  for (int k = 0; k < 16; k++) {
    float dx = nx[k] - mx, dy = ny[k] - my, dz = nz[k] - mz;
    c00 += dx * dx; c01 += dx * dy; c02 += dx * dz;
    c11 += dy * dy; c12 += dy * dz; c22 += dz * dz;
  }
  size_t row = (size_t)b * NPTS + q;
  float* xo = x0 + row * 12;
  xo[0] = qx;  xo[1] = qy;  xo[2] = qz;
  xo[3] = c00; xo[4] = c01; xo[5] = c02;
  xo[6] = c01; xo[7] = c11; xo[8] = c12;
  xo[9] = c02; xo[10] = c12; xo[11] = c22;
  int* io = idxo + row * 16;
#pragma unroll
  for (int k = 0; k < 16; k++) io[k] = (int)si[k][t];
}

// ---------------- Kernel 2: MLP1 12->64->64->64 (relu each) ------------------
__global__ __launch_bounds__(128)
void k_mlp1(const float* __restrict__ x0,
            const float* __restrict__ w1, const float* __restrict__ b1,
            const float* __restrict__ w2, const float* __restrict__ b2,
            const float* __restrict__ w3, const float* __restrict__ b3,
            float* __restrict__ h3o) {
  __shared__ float s1[64 * 12], s2[64 * 64], s3[64 * 64];
  __shared__ float sb1[64], sb2[64], sb3[64];
  for (int i = threadIdx.x; i < 64 * 12; i += 128) s1[i] = w1[i];
  for (int i = threadIdx.x; i < 64 * 64; i += 128) { s2[i] = w2[i]; s3[i] = w3[i]; }
  if (threadIdx.x < 64) {
    sb1[threadIdx.x] = b1[threadIdx.x];
    sb2[threadIdx.x] = b2[threadIdx.x];
    sb3[threadIdx.x] = b3[threadIdx.x];
  }
  __syncthreads();

  size_t p = (size_t)blockIdx.x * 128 + threadIdx.x;
  const float4* xv = (const float4*)(x0 + p * 12);
  float4 xa = xv[0], xb = xv[1], xc = xv[2];

  float h[64];
#pragma unroll
  for (int o = 0; o < 64; o++) {
    const float4* wr = (const float4*)(s1 + o * 12);
    float a = sb1[o] + dot4(wr[0], xa) + dot4(wr[1], xb) + dot4(wr[2], xc);
    h[o] = fmaxf(a, 0.f);
  }
  float g[64];
#pragma unroll
  for (int o = 0; o < 64; o++) {
    float a = sb2[o];
    const float4* wr = (const float4*)(s2 + o * 64);
#pragma unroll
    for (int c4 = 0; c4 < 16; c4++) {
      float4 w = wr[c4];
      a += w.x * h[4 * c4] + w.y * h[4 * c4 + 1] + w.z * h[4 * c4 + 2] + w.w * h[4 * c4 + 3];
    }
    g[o] = fmaxf(a, 0.f);
  }
  float* out = h3o + p * 64;
  for (int o = 0; o < 64; o++) {   // dynamic o ok: global write, static g reads
    float a = sb3[o];
    const float4* wr = (const float4*)(s3 + o * 64);
#pragma unroll
    for (int c4 = 0; c4 < 16; c4++) {
      float4 w = wr[c4];
      a += w.x * g[4 * c4] + w.y * g[4 * c4 + 1] + w.z * g[4 * c4 + 2] + w.w * g[4 * c4 + 3];
    }
    out[o] = fmaxf(a, 0.f);
  }
}

// -------- Kernel 3: maxpool(h3,idx) -> lw1 (lin) -> relu(cw1) -> z[...,128] --
__global__ __launch_bounds__(128)
void k_graph1(const float* __restrict__ h3, const int* __restrict__ idx,
              const float* __restrict__ lw1, const float* __restrict__ lb1,
              const float* __restrict__ cw1, const float* __restrict__ cb1,
              float* __restrict__ z) {
  __shared__ float sl[64 * 64], sc[128 * 64];
  __shared__ float sbl[64], sbc[128];
  for (int i = threadIdx.x; i < 64 * 64; i += 128) sl[i] = lw1[i];
  for (int i = threadIdx.x; i < 128 * 64; i += 128) sc[i] = cw1[i];
  if (threadIdx.x < 64) sbl[threadIdx.x] = lb1[threadIdx.x];
  if (threadIdx.x < 128) sbc[threadIdx.x] = cb1[threadIdx.x];
  __syncthreads();

  size_t p = (size_t)blockIdx.x * 128 + threadIdx.x;
  int b = (int)(p >> 12);
  const int* ip = idx + p * 16;

  float m[64];
#pragma unroll
  for (int c = 0; c < 64; c++) m[c] = -3.0e38f;
  for (int k = 0; k < 16; k++) {
    const float4* nb = (const float4*)(h3 + (((size_t)b << 12) + ip[k]) * 64);
#pragma unroll
    for (int c4 = 0; c4 < 16; c4++) {
      float4 v = nb[c4];
      m[4 * c4]     = fmaxf(m[4 * c4], v.x);
      m[4 * c4 + 1] = fmaxf(m[4 * c4 + 1], v.y);
      m[4 * c4 + 2] = fmaxf(m[4 * c4 + 2], v.z);
      m[4 * c4 + 3] = fmaxf(m[4 * c4 + 3], v.w);
    }
  }
  float y[64];
#pragma unroll
  for (int o = 0; o < 64; o++) {
    float a = sbl[o];
    const float4* wr = (const float4*)(sl + o * 64);
#pragma unroll
    for (int c4 = 0; c4 < 16; c4++) {
      float4 w = wr[c4];
      a += w.x * m[4 * c4] + w.y * m[4 * c4 + 1] + w.z * m[4 * c4 + 2] + w.w * m[4 * c4 + 3];
    }
    y[o] = a;   // no relu on lw1
  }
  float* zo = z + p * 128;
  for (int o = 0; o < 128; o++) {
    float a = sbc[o];
    const float4* wr = (const float4*)(sc + o * 64);
#pragma unroll
    for (int c4 = 0; c4 < 16; c4++) {
      float4 w = wr[c4];
      a += w.x * y[4 * c4] + w.y * y[4 * c4 + 1] + w.z * y[4 * c4 + 2] + w.w * y[4 * c4 + 3];
    }
    zo[o] = fmaxf(a, 0.f);
  }
}

// ------ Kernel 4: maxpool(z,idx) -> lw2 -> cw2 -> global max (atomic) --------
// block = 64 points of one batch; LDS exactly 64 KB.
__global__ __launch_bounds__(256)
void k_graph2(const float* __restrict__ z, const int* __restrict__ idx,
              const float* __restrict__ lw2, const float* __restrict__ lb2,
              const float* __restrict__ cw2, const float* __restrict__ cb2,
              unsigned* __restrict__ gacc) {
  __shared__ float smT[128][64];   // transposed: [channel][point]  32 KB
  __shared__ float st[64][128];    // [point][channel]              32 KB

  const int b = blockIdx.x >> 6;
  const int pbase = (blockIdx.x & 63) * 64;
  const int t = threadIdx.x;

  // Phase A: neighbor maxpool of z -> smT
  {
    const int pl = t & 63, cg = t >> 6;   // 4 channel-groups of 32
    size_t p = (size_t)b * NPTS + pbase + pl;
    const int* ip = idx + p * 16;
    float mv[32];
#pragma unroll
    for (int c = 0; c < 32; c++) mv[c] = -3.0e38f;
    for (int k = 0; k < 16; k++) {
      const float4* nb = (const float4*)(z + ((size_t)b * NPTS + ip[k]) * 128 + cg * 32);
#pragma unroll
      for (int c4 = 0; c4 < 8; c4++) {
        float4 v = nb[c4];
        mv[4 * c4]     = fmaxf(mv[4 * c4], v.x);
        mv[4 * c4 + 1] = fmaxf(mv[4 * c4 + 1], v.y);
        mv[4 * c4 + 2] = fmaxf(mv[4 * c4 + 2], v.z);
        mv[4 * c4 + 3] = fmaxf(mv[4 * c4 + 3], v.w);
      }
    }
#pragma unroll
    for (int c = 0; c < 32; c++) smT[cg * 32 + c][pl] = mv[c];
  }
  __syncthreads();

  // Phase B: st[p][o] = lb2[o] + sum_c lw2[o][c]*m[p][c]  (no relu)
  {
    const int pl = t & 63, og = t >> 6;   // 4 output-groups of 32
    float acc[32];
#pragma unroll
    for (int oi = 0; oi < 32; oi++) acc[oi] = lb2[og * 32 + oi];
    for (int cb = 0; cb < 4; cb++) {
      float mr[32];
#pragma unroll
      for (int j = 0; j < 32; j++) mr[j] = smT[cb * 32 + j][pl];
#pragma unroll
      for (int oi = 0; oi < 32; oi++) {
        const float4* wr = (const float4*)(lw2 + (size_t)(og * 32 + oi) * 128 + cb * 32);
#pragma unroll
        for (int j4 = 0; j4 < 8; j4++) {
          float4 w = wr[j4];
          acc[oi] += w.x * mr[4 * j4] + w.y * mr[4 * j4 + 1] + w.z * mr[4 * j4 + 2] + w.w * mr[4 * j4 + 3];
        }
      }
    }
#pragma unroll
    for (int oi = 0; oi < 32; oi++) st[pl][og * 32 + oi] = acc[oi];
  }
  __syncthreads();

  // Phase C: u[o] = cb2[o] + cw2[o].st[p]; max over 64 points; atomic global max
  {
    float bias[4], best[4];
#pragma unroll
    for (int oi = 0; oi < 4; oi++) {
      bias[oi] = cb2[t * 4 + oi];
      best[oi] = -3.0e38f;
    }
    for (int p8 = 0; p8 < 64; p8 += 8) {
      float acc[4][8];
#pragma unroll
      for (int oi = 0; oi < 4; oi++)
#pragma unroll
        for (int pp = 0; pp < 8; pp++) acc[oi][pp] = bias[oi];
      for (int c4 = 0; c4 < 32; c4++) {
        float4 tv[8];
#pragma unroll
        for (int pp = 0; pp < 8; pp++) tv[pp] = *(const float4*)&st[p8 + pp][c4 * 4];
#pragma unroll
        for (int oi = 0; oi < 4; oi++) {
          float4 w = *(const float4*)&cw2[(size_t)(t * 4 + oi) * 128 + c4 * 4];
#pragma unroll
          for (int pp = 0; pp < 8; pp++) acc[oi][pp] += dot4(w, tv[pp]);
        }
      }
#pragma unroll
      for (int oi = 0; oi < 4; oi++)
#pragma unroll
        for (int pp = 0; pp < 8; pp++) best[oi] = fmaxf(best[oi], acc[oi][pp]);
    }
#pragma unroll
    for (int oi = 0; oi < 4; oi++)
      atomicMax(&gacc[b * 1024 + t * 4 + oi], fenc(best[oi]));
  }
}

// ---------------- Kernel 5: head MLP 1024 -> 512(relu) -> 512 ----------------
__global__ __launch_bounds__(512)
void k_head(const unsigned* __restrict__ gacc,
            const float* __restrict__ mw1, const float* __restrict__ mb1,
            const float* __restrict__ mw2, const float* __restrict__ mb2,
            float* __restrict__ out) {
  __shared__ float g[1024];
  __shared__ float h[512];
  const int b = blockIdx.x, t = threadIdx.x;
  for (int i = t; i < 1024; i += 512) g[i] = fdec(gacc[b * 1024 + i]);
  __syncthreads();
  float a = mb1[t];
  const float4* wr = (const float4*)(mw1 + (size_t)t * 1024);
  const float4* gv = (const float4*)g;
#pragma unroll 8
  for (int c4 = 0; c4 < 256; c4++) a += dot4(wr[c4], gv[c4]);
  h[t] = fmaxf(a, 0.f);
  __syncthreads();
  float a2 = mb2[t];
  const float4* wr2 = (const float4*)(mw2 + (size_t)t * 512);
  const float4* hv = (const float4*)h;
#pragma unroll 8
  for (int c4 = 0; c4 < 128; c4++) a2 += dot4(wr2[c4], hv[c4]);
  out[(size_t)b * 512 + t] = a2;
}

extern "C" void kernel_launch(void* const* d_in, const int* in_sizes, int n_in,
                              void* d_out, int out_size, void* d_ws, size_t ws_size,
                              hipStream_t stream) {
  const float* pts = (const float*)d_in[0];
  const float* w1  = (const float*)d_in[1];
  const float* b1  = (const float*)d_in[2];
  const float* w2  = (const float*)d_in[3];
  const float* b2  = (const float*)d_in[4];
  const float* w3  = (const float*)d_in[5];
  const float* b3  = (const float*)d_in[6];
  const float* lw1 = (const float*)d_in[7];
  const float* lb1 = (const float*)d_in[8];
  const float* cw1 = (const float*)d_in[9];
  const float* cb1 = (const float*)d_in[10];
  const float* lw2 = (const float*)d_in[11];
  const float* lb2 = (const float*)d_in[12];
  const float* cw2 = (const float*)d_in[13];
  const float* cb2 = (const float*)d_in[14];
  const float* mw1 = (const float*)d_in[15];
  const float* mb1 = (const float*)d_in[16];
  const float* mw2 = (const float*)d_in[17];
  const float* mb2 = (const float*)d_in[18];

  char* ws = (char*)d_ws;
  int*      idx  = (int*)(ws);                                    // 2 MB
  float*    x0   = (float*)(ws + 2097152);                        // 1.5 MB
  float*    h3   = (float*)(ws + 2097152 + 1572864);              // 8 MB
  float*    z    = (float*)(ws + 2097152 + 1572864 + 8388608);    // 16 MB
  unsigned* gacc = (unsigned*)(ws + 2097152 + 1572864 + 8388608 + 16777216);

  hipMemsetAsync(gacc, 0, NBATCH * 1024 * sizeof(unsigned), stream);
  k_knn<<<NBATCH * (NPTS / 128), 128, 0, stream>>>(pts, idx, x0);
  k_mlp1<<<(NBATCH * NPTS) / 128, 128, 0, stream>>>(x0, w1, b1, w2, b2, w3, b3, h3);
  k_graph1<<<(NBATCH * NPTS) / 128, 128, 0, stream>>>(h3, idx, lw1, lb1, cw1, cb1, z);
  k_graph2<<<NBATCH * (NPTS / 64), 256, 0, stream>>>(z, idx, lw2, lb2, cw2, cb2, gacc);
  k_head<<<NBATCH, 512, 0, stream>>>(gacc, mw1, mb1, mw2, mb2, (float*)d_out);
}

// Round 6
// 1329.615 us; speedup vs baseline: 1.7064x; 1.7064x over previous
//
#include <hip/hip_runtime.h>

#define NPTS 4096
#define NBATCH 8

__device__ __forceinline__ unsigned fenc(float f) {
  unsigned u = __float_as_uint(f);
  return (u & 0x80000000u) ? ~u : (u | 0x80000000u);
}
__device__ __forceinline__ float fdec(unsigned e) {
  unsigned u = (e & 0x80000000u) ? (e ^ 0x80000000u) : ~e;
  return __uint_as_float(u);
}
__device__ __forceinline__ float dot4(float4 a, float4 b) {
  return a.x * b.x + a.y * b.y + a.z * b.z + a.w * b.w;
}

// ---------------- Kernel 1: exact 16-NN + covariance features ----------------
// thread-per-query. Coords as float4{x,y,z,sq} in LDS (1 ds_read_b128
// broadcast per candidate). Selection: register-resident sorted top-16 +
// per-lane LDS append buffer; bitonic sort16 + bitonic merge when any lane's
// buffer is near-full. Exact: stale `worst` only over-accepts.
__global__ __launch_bounds__(128)
void k_knn(const float* __restrict__ pts, int* __restrict__ idxo,
           float* __restrict__ x0) {
  __shared__ float4 sp[NPTS];                 // 64 KB {x,y,z,sq}
  __shared__ float bufd[16][128];             // 8 KB
  __shared__ unsigned short bufi[16][128];    // 4 KB

  const int b = blockIdx.x >> 5;              // /32 chunks
  const int ch = blockIdx.x & 31;
  const float* pb = pts + (size_t)b * NPTS * 3;
  for (int i = threadIdx.x; i < NPTS; i += 128) {
    float x = pb[3 * i], y = pb[3 * i + 1], z = pb[3 * i + 2];
    sp[i] = make_float4(x, y, z, x * x + y * y + z * z);
  }
  __syncthreads();

  const int t = threadIdx.x;
  const int q = ch * 128 + t;
  const float4 qp = sp[q];
  const float qs = qp.w;

  float td[16];
  int ti[16];
#pragma unroll
  for (int j = 0; j < 16; j++) { td[j] = 3.0e38f; ti[j] = 0; }
  float worst = 3.0e38f;
  int cnt = 0;

  auto merge = [&]() {
    float bd[16];
    int bi[16];
#pragma unroll
    for (int j = 0; j < 16; j++) {
      bool v = j < cnt;
      float dv = bufd[j][t];
      int iv = (int)bufi[j][t];
      bd[j] = v ? dv : 3.0e38f;
      bi[j] = v ? iv : 0;
    }
    cnt = 0;
    // bitonic sort bd ascending (all indices compile-time)
#pragma unroll
    for (int k = 2; k <= 16; k <<= 1) {
#pragma unroll
      for (int j = k >> 1; j > 0; j >>= 1) {
#pragma unroll
        for (int i = 0; i < 16; i++) {
          int l = i ^ j;
          if (l > i) {
            bool dir = ((i & k) == 0);
            bool sw = dir ? (bd[i] > bd[l]) : (bd[i] < bd[l]);
            float fd = sw ? bd[l] : bd[i];
            float fl = sw ? bd[i] : bd[l];
            int gd = sw ? bi[l] : bi[i];
            int gl = sw ? bi[i] : bi[l];
            bd[i] = fd; bd[l] = fl; bi[i] = gd; bi[l] = gl;
          }
        }
      }
    }
    // cross step: keep the 16 smallest of {td (asc), bd (asc)} in td (bitonic)
#pragma unroll
    for (int i = 0; i < 16; i++) {
      int l = 15 - i;
      bool sw = bd[l] < td[i];
      td[i] = sw ? bd[l] : td[i];
      ti[i] = sw ? bi[l] : ti[i];
    }
    // bitonic clean -> ascending
#pragma unroll
    for (int j = 8; j > 0; j >>= 1) {
#pragma unroll
      for (int i = 0; i < 16; i++) {
        int l = i ^ j;
        if (l > i) {
          bool sw = td[i] > td[l];
          float fd = sw ? td[l] : td[i];
          float fl = sw ? td[i] : td[l];
          int gd = sw ? ti[l] : ti[i];
          int gl = sw ? ti[i] : ti[l];
          td[i] = fd; td[l] = fl; ti[i] = gd; ti[l] = gl;
        }
      }
    }
    worst = td[15];
  };

  for (int i0 = 0; i0 < NPTS; i0 += 4) {
    float d[4];
#pragma unroll
    for (int u = 0; u < 4; u++) {
      float4 c = sp[i0 + u];
      float dot = qp.x * c.x + qp.y * c.y + qp.z * c.z;
      d[u] = (qs + c.w) - 2.0f * dot;   // reference expansion
    }
#pragma unroll
    for (int u = 0; u < 4; u++) {
      if (d[u] < worst) {               // strict <: earlier index wins ties
        bufd[cnt][t] = d[u];
        bufi[cnt][t] = (unsigned short)(i0 + u);
        cnt++;
      }
    }
    if (__any(cnt >= 13)) merge();      // next group adds <=4; never overflows
  }
  if (__any(cnt > 0)) merge();

  // covariance of mean-centered neighbors
  float nx[16], ny[16], nz[16];
  float mx = 0.f, my = 0.f, mz = 0.f;
#pragma unroll
  for (int k = 0; k < 16; k++) {
    float4 c = sp[ti[k]];
    nx[k] = c.x; ny[k] = c.y; nz[k] = c.z;
    mx += c.x; my += c.y; mz += c.z;
  }
  mx *= 0.0625f; my *= 0.0625f; mz *= 0.0625f;
  float c00 = 0, c01 = 0, c02 = 0, c11 = 0, c12 = 0, c22 = 0;
#pragma unroll
  for (int k = 0; k < 16; k++) {
    float dx = nx[k] - mx, dy = ny[k] - my, dz = nz[k] - mz;
    c00 += dx * dx; c01 += dx * dy; c02 += dx * dz;
    c11 += dy * dy; c12 += dy * dz; c22 += dz * dz;
  }
  size_t row = (size_t)b * NPTS + q;
  float* xo = x0 + row * 12;
  xo[0] = qp.x; xo[1] = qp.y; xo[2] = qp.z;
  xo[3] = c00;  xo[4] = c01;  xo[5] = c02;
  xo[6] = c01;  xo[7] = c11;  xo[8] = c12;
  xo[9] = c02;  xo[10] = c12; xo[11] = c22;
  int* io = idxo + row * 16;
#pragma unroll
  for (int k = 0; k < 16; k++) io[k] = ti[k];
}

// ---------------- Kernel 2: MLP1 12->64->64->64 (relu each) ------------------
__global__ __launch_bounds__(128)
void k_mlp1(const float* __restrict__ x0,
            const float* __restrict__ w1, const float* __restrict__ b1,
            const float* __restrict__ w2, const float* __restrict__ b2,
            const float* __restrict__ w3, const float* __restrict__ b3,
            float* __restrict__ h3o) {
  __shared__ float s1[64 * 12], s2[64 * 64], s3[64 * 64];
  __shared__ float sb1[64], sb2[64], sb3[64];
  for (int i = threadIdx.x; i < 64 * 12; i += 128) s1[i] = w1[i];
  for (int i = threadIdx.x; i < 64 * 64; i += 128) { s2[i] = w2[i]; s3[i] = w3[i]; }
  if (threadIdx.x < 64) {
    sb1[threadIdx.x] = b1[threadIdx.x];
    sb2[threadIdx.x] = b2[threadIdx.x];
    sb3[threadIdx.x] = b3[threadIdx.x];
  }
  __syncthreads();

  size_t p = (size_t)blockIdx.x * 128 + threadIdx.x;
  const float4* xv = (const float4*)(x0 + p * 12);
  float4 xa = xv[0], xb = xv[1], xc = xv[2];

  float h[64];
#pragma unroll
  for (int o = 0; o < 64; o++) {
    const float4* wr = (const float4*)(s1 + o * 12);
    float a = sb1[o] + dot4(wr[0], xa) + dot4(wr[1], xb) + dot4(wr[2], xc);
    h[o] = fmaxf(a, 0.f);
  }
  float g[64];
#pragma unroll
  for (int o = 0; o < 64; o++) {
    float a = sb2[o];
    const float4* wr = (const float4*)(s2 + o * 64);
#pragma unroll
    for (int c4 = 0; c4 < 16; c4++) {
      float4 w = wr[c4];
      a += w.x * h[4 * c4] + w.y * h[4 * c4 + 1] + w.z * h[4 * c4 + 2] + w.w * h[4 * c4 + 3];
    }
    g[o] = fmaxf(a, 0.f);
  }
  float* out = h3o + p * 64;
  for (int o = 0; o < 64; o++) {
    float a = sb3[o];
    const float4* wr = (const float4*)(s3 + o * 64);
#pragma unroll
    for (int c4 = 0; c4 < 16; c4++) {
      float4 w = wr[c4];
      a += w.x * g[4 * c4] + w.y * g[4 * c4 + 1] + w.z * g[4 * c4 + 2] + w.w * g[4 * c4 + 3];
    }
    out[o] = fmaxf(a, 0.f);
  }
}

// -------- Kernel 3: maxpool(h3,idx) -> lw1 (lin) -> relu(cw1) -> z[...,128] --
__global__ __launch_bounds__(128)
void k_graph1(const float* __restrict__ h3, const int* __restrict__ idx,
              const float* __restrict__ lw1, const float* __restrict__ lb1,
              const float* __restrict__ cw1, const float* __restrict__ cb1,
              float* __restrict__ z) {
  __shared__ float sl[64 * 64], sc[128 * 64];
  __shared__ float sbl[64], sbc[128];
  for (int i = threadIdx.x; i < 64 * 64; i += 128) sl[i] = lw1[i];
  for (int i = threadIdx.x; i < 128 * 64; i += 128) sc[i] = cw1[i];
  if (threadIdx.x < 64) sbl[threadIdx.x] = lb1[threadIdx.x];
  if (threadIdx.x < 128) sbc[threadIdx.x] = cb1[threadIdx.x];
  __syncthreads();

  size_t p = (size_t)blockIdx.x * 128 + threadIdx.x;
  int b = (int)(p >> 12);
  const int* ip = idx + p * 16;

  float m[64];
#pragma unroll
  for (int c = 0; c < 64; c++) m[c] = -3.0e38f;
  for (int k = 0; k < 16; k++) {
    const float4* nb = (const float4*)(h3 + (((size_t)b << 12) + ip[k]) * 64);
#pragma unroll
    for (int c4 = 0; c4 < 16; c4++) {
      float4 v = nb[c4];
      m[4 * c4]     = fmaxf(m[4 * c4], v.x);
      m[4 * c4 + 1] = fmaxf(m[4 * c4 + 1], v.y);
      m[4 * c4 + 2] = fmaxf(m[4 * c4 + 2], v.z);
      m[4 * c4 + 3] = fmaxf(m[4 * c4 + 3], v.w);
    }
  }
  float y[64];
#pragma unroll
  for (int o = 0; o < 64; o++) {
    float a = sbl[o];
    const float4* wr = (const float4*)(sl + o * 64);
#pragma unroll
    for (int c4 = 0; c4 < 16; c4++) {
      float4 w = wr[c4];
      a += w.x * m[4 * c4] + w.y * m[4 * c4 + 1] + w.z * m[4 * c4 + 2] + w.w * m[4 * c4 + 3];
    }
    y[o] = a;   // no relu on lw1
  }
  float* zo = z + p * 128;
  for (int o = 0; o < 128; o++) {
    float a = sbc[o];
    const float4* wr = (const float4*)(sc + o * 64);
#pragma unroll
    for (int c4 = 0; c4 < 16; c4++) {
      float4 w = wr[c4];
      a += w.x * y[4 * c4] + w.y * y[4 * c4 + 1] + w.z * y[4 * c4 + 2] + w.w * y[4 * c4 + 3];
    }
    zo[o] = fmaxf(a, 0.f);
  }
}

// ------ Kernel 4: maxpool(z,idx) -> lw2 -> cw2 -> global max (atomic) --------
// block = 64 points of one batch; LDS exactly 64 KB.
__global__ __launch_bounds__(256)
void k_graph2(const float* __restrict__ z, const int* __restrict__ idx,
              const float* __restrict__ lw2, const float* __restrict__ lb2,
              const float* __restrict__ cw2, const float* __restrict__ cb2,
              unsigned* __restrict__ gacc) {
  __shared__ float smT[128][64];   // transposed: [channel][point]  32 KB
  __shared__ float st[64][128];    // [point][channel]              32 KB

  const int b = blockIdx.x >> 6;
  const int pbase = (blockIdx.x & 63) * 64;
  const int t = threadIdx.x;

  // Phase A: neighbor maxpool of z -> smT
  {
    const int pl = t & 63, cg = t >> 6;
    size_t p = (size_t)b * NPTS + pbase + pl;
    const int* ip = idx + p * 16;
    float mv[32];
#pragma unroll
    for (int c = 0; c < 32; c++) mv[c] = -3.0e38f;
    for (int k = 0; k < 16; k++) {
      const float4* nb = (const float4*)(z + ((size_t)b * NPTS + ip[k]) * 128 + cg * 32);
#pragma unroll
      for (int c4 = 0; c4 < 8; c4++) {
        float4 v = nb[c4];
        mv[4 * c4]     = fmaxf(mv[4 * c4], v.x);
        mv[4 * c4 + 1] = fmaxf(mv[4 * c4 + 1], v.y);
        mv[4 * c4 + 2] = fmaxf(mv[4 * c4 + 2], v.z);
        mv[4 * c4 + 3] = fmaxf(mv[4 * c4 + 3], v.w);
      }
    }
#pragma unroll
    for (int c = 0; c < 32; c++) smT[cg * 32 + c][pl] = mv[c];
  }
  __syncthreads();

  // Phase B: st[p][o] = lb2[o] + sum_c lw2[o][c]*m[p][c]
  {
    const int pl = t & 63, og = t >> 6;
    float acc[32];
#pragma unroll
    for (int oi = 0; oi < 32; oi++) acc[oi] = lb2[og * 32 + oi];
    for (int cb = 0; cb < 4; cb++) {
      float mr[32];
#pragma unroll
      for (int j = 0; j < 32; j++) mr[j] = smT[cb * 32 + j][pl];
#pragma unroll
      for (int oi = 0; oi < 32; oi++) {
        const float4* wr = (const float4*)(lw2 + (size_t)(og * 32 + oi) * 128 + cb * 32);
#pragma unroll
        for (int j4 = 0; j4 < 8; j4++) {
          float4 w = wr[j4];
          acc[oi] += w.x * mr[4 * j4] + w.y * mr[4 * j4 + 1] + w.z * mr[4 * j4 + 2] + w.w * mr[4 * j4 + 3];
        }
      }
    }
#pragma unroll
    for (int oi = 0; oi < 32; oi++) st[pl][og * 32 + oi] = acc[oi];
  }
  __syncthreads();

  // Phase C: u[o] = cb2[o] + cw2[o].st[p]; max over 64 points; atomic max
  {
    float bias[4], best[4];
#pragma unroll
    for (int oi = 0; oi < 4; oi++) {
      bias[oi] = cb2[t * 4 + oi];
      best[oi] = -3.0e38f;
    }
    for (int p8 = 0; p8 < 64; p8 += 8) {
      float acc[4][8];
#pragma unroll
      for (int oi = 0; oi < 4; oi++)
#pragma unroll
        for (int pp = 0; pp < 8; pp++) acc[oi][pp] = bias[oi];
      for (int c4 = 0; c4 < 32; c4++) {
        float4 tv[8];
#pragma unroll
        for (int pp = 0; pp < 8; pp++) tv[pp] = *(const float4*)&st[p8 + pp][c4 * 4];
#pragma unroll
        for (int oi = 0; oi < 4; oi++) {
          float4 w = *(const float4*)&cw2[(size_t)(t * 4 + oi) * 128 + c4 * 4];
#pragma unroll
          for (int pp = 0; pp < 8; pp++) acc[oi][pp] += dot4(w, tv[pp]);
        }
      }
#pragma unroll
      for (int oi = 0; oi < 4; oi++)
#pragma unroll
        for (int pp = 0; pp < 8; pp++) best[oi] = fmaxf(best[oi], acc[oi][pp]);
    }
#pragma unroll
    for (int oi = 0; oi < 4; oi++)
      atomicMax(&gacc[b * 1024 + t * 4 + oi], fenc(best[oi]));
  }
}

// ---------------- Kernel 5: head MLP 1024 -> 512(relu) -> 512 ----------------
__global__ __launch_bounds__(512)
void k_head(const unsigned* __restrict__ gacc,
            const float* __restrict__ mw1, const float* __restrict__ mb1,
            const float* __restrict__ mw2, const float* __restrict__ mb2,
            float* __restrict__ out) {
  __shared__ float g[1024];
  __shared__ float h[512];
  const int b = blockIdx.x, t = threadIdx.x;
  for (int i = t; i < 1024; i += 512) g[i] = fdec(gacc[b * 1024 + i]);
  __syncthreads();
  float a = mb1[t];
  const float4* wr = (const float4*)(mw1 + (size_t)t * 1024);
  const float4* gv = (const float4*)g;
#pragma unroll 8
  for (int c4 = 0; c4 < 256; c4++) a += dot4(wr[c4], gv[c4]);
  h[t] = fmaxf(a, 0.f);
  __syncthreads();
  float a2 = mb2[t];
  const float4* wr2 = (const float4*)(mw2 + (size_t)t * 512);
  const float4* hv = (const float4*)h;
#pragma unroll 8
  for (int c4 = 0; c4 < 128; c4++) a2 += dot4(wr2[c4], hv[c4]);
  out[(size_t)b * 512 + t] = a2;
}

extern "C" void kernel_launch(void* const* d_in, const int* in_sizes, int n_in,
                              void* d_out, int out_size, void* d_ws, size_t ws_size,
                              hipStream_t stream) {
  const float* pts = (const float*)d_in[0];
  const float* w1  = (const float*)d_in[1];
  const float* b1  = (const float*)d_in[2];
  const float* w2  = (const float*)d_in[3];
  const float* b2  = (const float*)d_in[4];
  const float* w3  = (const float*)d_in[5];
  const float* b3  = (const float*)d_in[6];
  const float* lw1 = (const float*)d_in[7];
  const float* lb1 = (const float*)d_in[8];
  const float* cw1 = (const float*)d_in[9];
  const float* cb1 = (const float*)d_in[10];
  const float* lw2 = (const float*)d_in[11];
  const float* lb2 = (const float*)d_in[12];
  const float* cw2 = (const float*)d_in[13];
  const float* cb2 = (const float*)d_in[14];
  const float* mw1 = (const float*)d_in[15];
  const float* mb1 = (const float*)d_in[16];
  const float* mw2 = (const float*)d_in[17];
  const float* mb2 = (const float*)d_in[18];

  char* ws = (char*)d_ws;
  int*      idx  = (int*)(ws);                                    // 2 MB
  float*    x0   = (float*)(ws + 2097152);                        // 1.5 MB
  float*    h3   = (float*)(ws + 2097152 + 1572864);              // 8 MB
  float*    z    = (float*)(ws + 2097152 + 1572864 + 8388608);    // 16 MB
  unsigned* gacc = (unsigned*)(ws + 2097152 + 1572864 + 8388608 + 16777216);

  hipMemsetAsync(gacc, 0, NBATCH * 1024 * sizeof(unsigned), stream);
  k_knn<<<NBATCH * (NPTS / 128), 128, 0, stream>>>(pts, idx, x0);
  k_mlp1<<<(NBATCH * NPTS) / 128, 128, 0, stream>>>(x0, w1, b1, w2, b2, w3, b3, h3);
  k_graph1<<<(NBATCH * NPTS) / 128, 128, 0, stream>>>(h3, idx, lw1, lb1, cw1, cb1, z);
  k_graph2<<<NBATCH * (NPTS / 64), 256, 0, stream>>>(z, idx, lw2, lb2, cw2, cb2, gacc);
  k_head<<<NBATCH, 512, 0, stream>>>(gacc, mw1, mb1, mw2, mb2, (float*)d_out);
}

// Round 8
// 876.385 us; speedup vs baseline: 2.5889x; 1.5172x over previous
//
#include <hip/hip_runtime.h>

#define NPTS 4096
#define NBATCH 8
#define STP 132   // padded st row stride (floats): 528B = 33*16B, float4-aligned, 8-way banks

__device__ __forceinline__ unsigned fenc(float f) {
  unsigned u = __float_as_uint(f);
  return (u & 0x80000000u) ? ~u : (u | 0x80000000u);
}
__device__ __forceinline__ float fdec(unsigned e) {
  unsigned u = (e & 0x80000000u) ? (e ^ 0x80000000u) : ~e;
  return __uint_as_float(u);
}
__device__ __forceinline__ float dot4(float4 a, float4 b) {
  return a.x * b.x + a.y * b.y + a.z * b.z + a.w * b.w;
}

// ---------------- Kernel 0: transpose cw2 [1024][128] -> cw2T [128][1024] ----
__global__ __launch_bounds__(256)
void k_tr(const float* __restrict__ cw2, float* __restrict__ cw2T) {
  int idx = blockIdx.x * 256 + threadIdx.x;   // over 128*1024
  int c = idx >> 10, o = idx & 1023;
  cw2T[idx] = cw2[o * 128 + c];
}

// ---------------- Kernel 1: exact 16-NN + covariance features ----------------
// thread-per-query. Coords as float4{x,y,z,sq} in LDS (1 ds_read_b128
// broadcast per candidate). Selection: register-resident sorted top-16 +
// per-lane LDS append buffer; bitonic sort16 + bitonic merge when any lane's
// buffer is near-full. Exact: stale `worst` only over-accepts.
__global__ __launch_bounds__(128)
void k_knn(const float* __restrict__ pts, int* __restrict__ idxo,
           float* __restrict__ x0) {
  __shared__ float4 sp[NPTS];                 // 64 KB {x,y,z,sq}
  __shared__ float bufd[16][128];             // 8 KB
  __shared__ unsigned short bufi[16][128];    // 4 KB

  const int b = blockIdx.x >> 5;              // /32 chunks
  const int ch = blockIdx.x & 31;
  const float* pb = pts + (size_t)b * NPTS * 3;
  for (int i = threadIdx.x; i < NPTS; i += 128) {
    float x = pb[3 * i], y = pb[3 * i + 1], z = pb[3 * i + 2];
    sp[i] = make_float4(x, y, z, x * x + y * y + z * z);
  }
  __syncthreads();

  const int t = threadIdx.x;
  const int q = ch * 128 + t;
  const float4 qp = sp[q];
  const float qs = qp.w;

  float td[16];
  int ti[16];
#pragma unroll
  for (int j = 0; j < 16; j++) { td[j] = 3.0e38f; ti[j] = 0; }
  float worst = 3.0e38f;
  int cnt = 0;

  auto merge = [&]() {
    float bd[16];
    int bi[16];
#pragma unroll
    for (int j = 0; j < 16; j++) {
      bool v = j < cnt;
      float dv = bufd[j][t];
      int iv = (int)bufi[j][t];
      bd[j] = v ? dv : 3.0e38f;
      bi[j] = v ? iv : 0;
    }
    cnt = 0;
    // bitonic sort bd ascending (all indices compile-time)
#pragma unroll
    for (int k = 2; k <= 16; k <<= 1) {
#pragma unroll
      for (int j = k >> 1; j > 0; j >>= 1) {
#pragma unroll
        for (int i = 0; i < 16; i++) {
          int l = i ^ j;
          if (l > i) {
            bool dir = ((i & k) == 0);
            bool sw = dir ? (bd[i] > bd[l]) : (bd[i] < bd[l]);
            float fd = sw ? bd[l] : bd[i];
            float fl = sw ? bd[i] : bd[l];
            int gd = sw ? bi[l] : bi[i];
            int gl = sw ? bi[i] : bi[l];
            bd[i] = fd; bd[l] = fl; bi[i] = gd; bi[l] = gl;
          }
        }
      }
    }
    // cross step: keep the 16 smallest of {td (asc), bd (asc)} in td (bitonic)
#pragma unroll
    for (int i = 0; i < 16; i++) {
      int l = 15 - i;
      bool sw = bd[l] < td[i];
      td[i] = sw ? bd[l] : td[i];
      ti[i] = sw ? bi[l] : ti[i];
    }
    // bitonic clean -> ascending
#pragma unroll
    for (int j = 8; j > 0; j >>= 1) {
#pragma unroll
      for (int i = 0; i < 16; i++) {
        int l = i ^ j;
        if (l > i) {
          bool sw = td[i] > td[l];
          float fd = sw ? td[l] : td[i];
          float fl = sw ? td[i] : td[l];
          int gd = sw ? ti[l] : ti[i];
          int gl = sw ? ti[i] : ti[l];
          td[i] = fd; td[l] = fl; ti[i] = gd; ti[l] = gl;
        }
      }
    }
    worst = td[15];
  };

  for (int i0 = 0; i0 < NPTS; i0 += 4) {
    float d[4];
#pragma unroll
    for (int u = 0; u < 4; u++) {
      float4 c = sp[i0 + u];
      float dot = qp.x * c.x + qp.y * c.y + qp.z * c.z;
      d[u] = (qs + c.w) - 2.0f * dot;   // reference expansion
    }
#pragma unroll
    for (int u = 0; u < 4; u++) {
      if (d[u] < worst) {               // strict <: earlier index wins ties
        bufd[cnt][t] = d[u];
        bufi[cnt][t] = (unsigned short)(i0 + u);
        cnt++;
      }
    }
    if (__any(cnt >= 13)) merge();      // next group adds <=4; never overflows
  }
  if (__any(cnt > 0)) merge();

  // covariance of mean-centered neighbors
  float nx[16], ny[16], nz[16];
  float mx = 0.f, my = 0.f, mz = 0.f;
#pragma unroll
  for (int k = 0; k < 16; k++) {
    float4 c = sp[ti[k]];
    nx[k] = c.x; ny[k] = c.y; nz[k] = c.z;
    mx += c.x; my += c.y; mz += c.z;
  }
  mx *= 0.0625f; my *= 0.0625f; mz *= 0.0625f;
  float c00 = 0, c01 = 0, c02 = 0, c11 = 0, c12 = 0, c22 = 0;
#pragma unroll
  for (int k = 0; k < 16; k++) {
    float dx = nx[k] - mx, dy = ny[k] - my, dz = nz[k] - mz;
    c00 += dx * dx; c01 += dx * dy; c02 += dx * dz;
    c11 += dy * dy; c12 += dy * dz; c22 += dz * dz;
  }
  size_t row = (size_t)b * NPTS + q;
  float* xo = x0 + row * 12;
  xo[0] = qp.x; xo[1] = qp.y; xo[2] = qp.z;
  xo[3] = c00;  xo[4] = c01;  xo[5] = c02;
  xo[6] = c01;  xo[7] = c11;  xo[8] = c12;
  xo[9] = c02;  xo[10] = c12; xo[11] = c22;
  int* io = idxo + row * 16;
#pragma unroll
  for (int k = 0; k < 16; k++) io[k] = ti[k];
}

// ---------------- Kernel 2: MLP1 12->64->64->64 (relu each) ------------------
__global__ __launch_bounds__(128)
void k_mlp1(const float* __restrict__ x0,
            const float* __restrict__ w1, const float* __restrict__ b1,
            const float* __restrict__ w2, const float* __restrict__ b2,
            const float* __restrict__ w3, const float* __restrict__ b3,
            float* __restrict__ h3o) {
  __shared__ float s1[64 * 12], s2[64 * 64], s3[64 * 64];
  __shared__ float sb1[64], sb2[64], sb3[64];
  for (int i = threadIdx.x; i < 64 * 12; i += 128) s1[i] = w1[i];
  for (int i = threadIdx.x; i < 64 * 64; i += 128) { s2[i] = w2[i]; s3[i] = w3[i]; }
  if (threadIdx.x < 64) {
    sb1[threadIdx.x] = b1[threadIdx.x];
    sb2[threadIdx.x] = b2[threadIdx.x];
    sb3[threadIdx.x] = b3[threadIdx.x];
  }
  __syncthreads();

  size_t p = (size_t)blockIdx.x * 128 + threadIdx.x;
  const float4* xv = (const float4*)(x0 + p * 12);
  float4 xa = xv[0], xb = xv[1], xc = xv[2];

  float h[64];
#pragma unroll
  for (int o = 0; o < 64; o++) {
    const float4* wr = (const float4*)(s1 + o * 12);
    float a = sb1[o] + dot4(wr[0], xa) + dot4(wr[1], xb) + dot4(wr[2], xc);
    h[o] = fmaxf(a, 0.f);
  }
  float g[64];
#pragma unroll
  for (int o = 0; o < 64; o++) {
    float a = sb2[o];
    const float4* wr = (const float4*)(s2 + o * 64);
#pragma unroll
    for (int c4 = 0; c4 < 16; c4++) {
      float4 w = wr[c4];
      a += w.x * h[4 * c4] + w.y * h[4 * c4 + 1] + w.z * h[4 * c4 + 2] + w.w * h[4 * c4 + 3];
    }
    g[o] = fmaxf(a, 0.f);
  }
  float* out = h3o + p * 64;
  for (int o = 0; o < 64; o++) {
    float a = sb3[o];
    const float4* wr = (const float4*)(s3 + o * 64);
#pragma unroll
    for (int c4 = 0; c4 < 16; c4++) {
      float4 w = wr[c4];
      a += w.x * g[4 * c4] + w.y * g[4 * c4 + 1] + w.z * g[4 * c4 + 2] + w.w * g[4 * c4 + 3];
    }
    out[o] = fmaxf(a, 0.f);
  }
}

// -------- Kernel 3: maxpool(h3,idx) -> lw1 (lin) -> relu(cw1) -> z[...,128] --
__global__ __launch_bounds__(128)
void k_graph1(const float* __restrict__ h3, const int* __restrict__ idx,
              const float* __restrict__ lw1, const float* __restrict__ lb1,
              const float* __restrict__ cw1, const float* __restrict__ cb1,
              float* __restrict__ z) {
  __shared__ float sl[64 * 64], sc[128 * 64];
  __shared__ float sbl[64], sbc[128];
  for (int i = threadIdx.x; i < 64 * 64; i += 128) sl[i] = lw1[i];
  for (int i = threadIdx.x; i < 128 * 64; i += 128) sc[i] = cw1[i];
  if (threadIdx.x < 64) sbl[threadIdx.x] = lb1[threadIdx.x];
  if (threadIdx.x < 128) sbc[threadIdx.x] = cb1[threadIdx.x];
  __syncthreads();

  size_t p = (size_t)blockIdx.x * 128 + threadIdx.x;
  int b = (int)(p >> 12);
  const int* ip = idx + p * 16;

  float m[64];
#pragma unroll
  for (int c = 0; c < 64; c++) m[c] = -3.0e38f;
  for (int k = 0; k < 16; k++) {
    const float4* nb = (const float4*)(h3 + (((size_t)b << 12) + ip[k]) * 64);
#pragma unroll
    for (int c4 = 0; c4 < 16; c4++) {
      float4 v = nb[c4];
      m[4 * c4]     = fmaxf(m[4 * c4], v.x);
      m[4 * c4 + 1] = fmaxf(m[4 * c4 + 1], v.y);
      m[4 * c4 + 2] = fmaxf(m[4 * c4 + 2], v.z);
      m[4 * c4 + 3] = fmaxf(m[4 * c4 + 3], v.w);
    }
  }
  float y[64];
#pragma unroll
  for (int o = 0; o < 64; o++) {
    float a = sbl[o];
    const float4* wr = (const float4*)(sl + o * 64);
#pragma unroll
    for (int c4 = 0; c4 < 16; c4++) {
      float4 w = wr[c4];
      a += w.x * m[4 * c4] + w.y * m[4 * c4 + 1] + w.z * m[4 * c4 + 2] + w.w * m[4 * c4 + 3];
    }
    y[o] = a;   // no relu on lw1
  }
  float* zo = z + p * 128;
  for (int o = 0; o < 128; o++) {
    float a = sbc[o];
    const float4* wr = (const float4*)(sc + o * 64);
#pragma unroll
    for (int c4 = 0; c4 < 16; c4++) {
      float4 w = wr[c4];
      a += w.x * y[4 * c4] + w.y * y[4 * c4 + 1] + w.z * y[4 * c4 + 2] + w.w * y[4 * c4 + 3];
    }
    zo[o] = fmaxf(a, 0.f);
  }
}

// ------ Kernel 4: maxpool(z,idx) -> lw2 -> cw2 -> global max (atomic) --------
// block = 64 points of one batch. Phase C uses transposed cw2T (coalesced).
__global__ __launch_bounds__(256)
void k_graph2(const float* __restrict__ z, const int* __restrict__ idx,
              const float* __restrict__ lw2, const float* __restrict__ lb2,
              const float* __restrict__ cw2T, const float* __restrict__ cb2,
              unsigned* __restrict__ gacc) {
  __shared__ float smT[128][64];   // transposed: [channel][point]  32 KB
  __shared__ float st[64][STP];    // [point][channel], padded      33 KB

  const int b = blockIdx.x >> 6;
  const int pbase = (blockIdx.x & 63) * 64;
  const int t = threadIdx.x;

  // Phase A: neighbor maxpool of z -> smT
  {
    const int pl = t & 63, cg = t >> 6;
    size_t p = (size_t)b * NPTS + pbase + pl;
    const int* ip = idx + p * 16;
    float mv[32];
#pragma unroll
    for (int c = 0; c < 32; c++) mv[c] = -3.0e38f;
    for (int k = 0; k < 16; k++) {
      const float4* nb = (const float4*)(z + ((size_t)b * NPTS + ip[k]) * 128 + cg * 32);
#pragma unroll
      for (int c4 = 0; c4 < 8; c4++) {
        float4 v = nb[c4];
        mv[4 * c4]     = fmaxf(mv[4 * c4], v.x);
        mv[4 * c4 + 1] = fmaxf(mv[4 * c4 + 1], v.y);
        mv[4 * c4 + 2] = fmaxf(mv[4 * c4 + 2], v.z);
        mv[4 * c4 + 3] = fmaxf(mv[4 * c4 + 3], v.w);
      }
    }
#pragma unroll
    for (int c = 0; c < 32; c++) smT[cg * 32 + c][pl] = mv[c];
  }
  __syncthreads();

  // Phase B: st[p][o] = lb2[o] + sum_c lw2[o][c]*m[p][c]  (float4 writes)
  {
    const int pl = t & 63, og = t >> 6;
    float acc[32];
#pragma unroll
    for (int oi = 0; oi < 32; oi++) acc[oi] = lb2[og * 32 + oi];
    for (int cb = 0; cb < 4; cb++) {
      float mr[32];
#pragma unroll
      for (int j = 0; j < 32; j++) mr[j] = smT[cb * 32 + j][pl];
#pragma unroll
      for (int oi = 0; oi < 32; oi++) {
        const float4* wr = (const float4*)(lw2 + (size_t)(og * 32 + oi) * 128 + cb * 32);
#pragma unroll
        for (int j4 = 0; j4 < 8; j4++) {
          float4 w = wr[j4];
          acc[oi] += w.x * mr[4 * j4] + w.y * mr[4 * j4 + 1] + w.z * mr[4 * j4 + 2] + w.w * mr[4 * j4 + 3];
        }
      }
    }
#pragma unroll
    for (int oi4 = 0; oi4 < 8; oi4++)
      *(float4*)&st[pl][og * 32 + oi4 * 4] =
          make_float4(acc[4 * oi4], acc[4 * oi4 + 1], acc[4 * oi4 + 2], acc[4 * oi4 + 3]);
  }
  __syncthreads();

  // Phase C: u[o] = cb2[o] + cw2T[:,o].st[p]; max over 64 points; atomic max
  // cw2T[c][o]: lane t reads float4 at col t*4 -> fully coalesced.
  {
    float bias[4], best[4];
#pragma unroll
    for (int oi = 0; oi < 4; oi++) {
      bias[oi] = cb2[t * 4 + oi];
      best[oi] = -3.0e38f;
    }
    for (int p8 = 0; p8 < 64; p8 += 8) {
      float acc[4][8];
#pragma unroll
      for (int oi = 0; oi < 4; oi++)
#pragma unroll
        for (int pp = 0; pp < 8; pp++) acc[oi][pp] = bias[oi];
      for (int c4 = 0; c4 < 32; c4++) {
        float4 sv[8];
#pragma unroll
        for (int pp = 0; pp < 8; pp++) sv[pp] = *(const float4*)&st[p8 + pp][c4 * 4];
        float4 w0 = *(const float4*)&cw2T[(size_t)(c4 * 4 + 0) * 1024 + t * 4];
        float4 w1 = *(const float4*)&cw2T[(size_t)(c4 * 4 + 1) * 1024 + t * 4];
        float4 w2 = *(const float4*)&cw2T[(size_t)(c4 * 4 + 2) * 1024 + t * 4];
        float4 w3 = *(const float4*)&cw2T[(size_t)(c4 * 4 + 3) * 1024 + t * 4];
#pragma unroll
        for (int pp = 0; pp < 8; pp++) {
          float4 s = sv[pp];
          acc[0][pp] += w0.x * s.x + w1.x * s.y + w2.x * s.z + w3.x * s.w;
          acc[1][pp] += w0.y * s.x + w1.y * s.y + w2.y * s.z + w3.y * s.w;
          acc[2][pp] += w0.z * s.x + w1.z * s.y + w2.z * s.z + w3.z * s.w;
          acc[3][pp] += w0.w * s.x + w1.w * s.y + w2.w * s.z + w3.w * s.w;
        }
      }
#pragma unroll
      for (int oi = 0; oi < 4; oi++)
#pragma unroll
        for (int pp = 0; pp < 8; pp++) best[oi] = fmaxf(best[oi], acc[oi][pp]);
    }
#pragma unroll
    for (int oi = 0; oi < 4; oi++)
      atomicMax(&gacc[b * 1024 + t * 4 + oi], fenc(best[oi]));
  }
}

// ---------------- Kernel 5: head MLP 1024 -> 512(relu) -> 512 ----------------
__global__ __launch_bounds__(512)
void k_head(const unsigned* __restrict__ gacc,
            const float* __restrict__ mw1, const float* __restrict__ mb1,
            const float* __restrict__ mw2, const float* __restrict__ mb2,
            float* __restrict__ out) {
  __shared__ float g[1024];
  __shared__ float h[512];
  const int b = blockIdx.x, t = threadIdx.x;
  for (int i = t; i < 1024; i += 512) g[i] = fdec(gacc[b * 1024 + i]);
  __syncthreads();
  float a = mb1[t];
  const float4* wr = (const float4*)(mw1 + (size_t)t * 1024);
  const float4* gv = (const float4*)g;
#pragma unroll 8
  for (int c4 = 0; c4 < 256; c4++) a += dot4(wr[c4], gv[c4]);
  h[t] = fmaxf(a, 0.f);
  __syncthreads();
  float a2 = mb2[t];
  const float4* wr2 = (const float4*)(mw2 + (size_t)t * 512);
  const float4* hv = (const float4*)h;
#pragma unroll 8
  for (int c4 = 0; c4 < 128; c4++) a2 += dot4(wr2[c4], hv[c4]);
  out[(size_t)b * 512 + t] = a2;
}

extern "C" void kernel_launch(void* const* d_in, const int* in_sizes, int n_in,
                              void* d_out, int out_size, void* d_ws, size_t ws_size,
                              hipStream_t stream) {
  const float* pts = (const float*)d_in[0];
  const float* w1  = (const float*)d_in[1];
  const float* b1  = (const float*)d_in[2];
  const float* w2  = (const float*)d_in[3];
  const float* b2  = (const float*)d_in[4];
  const float* w3  = (const float*)d_in[5];
  const float* b3  = (const float*)d_in[6];
  const float* lw1 = (const float*)d_in[7];
  const float* lb1 = (const float*)d_in[8];
  const float* cw1 = (const float*)d_in[9];
  const float* cb1 = (const float*)d_in[10];
  const float* lw2 = (const float*)d_in[11];
  const float* lb2 = (const float*)d_in[12];
  const float* cw2 = (const float*)d_in[13];
  const float* cb2 = (const float*)d_in[14];
  const float* mw1 = (const float*)d_in[15];
  const float* mb1 = (const float*)d_in[16];
  const float* mw2 = (const float*)d_in[17];
  const float* mb2 = (const float*)d_in[18];

  char* ws = (char*)d_ws;
  int*      idx  = (int*)(ws);                                    // 2 MB
  float*    x0   = (float*)(ws + 2097152);                        // 1.5 MB
  float*    h3   = (float*)(ws + 2097152 + 1572864);              // 8 MB
  float*    z    = (float*)(ws + 2097152 + 1572864 + 8388608);    // 16 MB
  unsigned* gacc = (unsigned*)(ws + 28835840);                    // 32 KB
  float*    cw2T = (float*)(ws + 28835840 + 32768);               // 512 KB

  hipMemsetAsync(gacc, 0, NBATCH * 1024 * sizeof(unsigned), stream);
  k_tr<<<512, 256, 0, stream>>>(cw2, cw2T);
  k_knn<<<NBATCH * (NPTS / 128), 128, 0, stream>>>(pts, idx, x0);
  k_mlp1<<<(NBATCH * NPTS) / 128, 128, 0, stream>>>(x0, w1, b1, w2, b2, w3, b3, h3);
  k_graph1<<<(NBATCH * NPTS) / 128, 128, 0, stream>>>(h3, idx, lw1, lb1, cw1, cb1, z);
  k_graph2<<<NBATCH * (NPTS / 64), 256, 0, stream>>>(z, idx, lw2, lb2, cw2T, cb2, gacc);
  k_head<<<NBATCH, 512, 0, stream>>>(gacc, mw1, mb1, mw2, mb2, (float*)d_out);
}

// Round 10
// 690.271 us; speedup vs baseline: 3.2869x; 1.2696x over previous
//
#include <hip/hip_runtime.h>

#define NPTS 4096
#define NBATCH 8
#define STP 132   // padded st row stride (floats): 528B = 33*16B, float4-aligned, 8-way banks

__device__ __forceinline__ unsigned fenc(float f) {
  unsigned u = __float_as_uint(f);
  return (u & 0x80000000u) ? ~u : (u | 0x80000000u);
}
__device__ __forceinline__ float fdec(unsigned e) {
  unsigned u = (e & 0x80000000u) ? (e ^ 0x80000000u) : ~e;
  return __uint_as_float(u);
}
__device__ __forceinline__ float dot4(float4 a, float4 b) {
  return a.x * b.x + a.y * b.y + a.z * b.z + a.w * b.w;
}

// ---------------- Kernel 0a: transpose cw2 [1024][128] -> cw2T [128][1024] ---
__global__ __launch_bounds__(256)
void k_tr(const float* __restrict__ cw2, float* __restrict__ cw2T) {
  int idx = blockIdx.x * 256 + threadIdx.x;   // over 128*1024
  int c = idx >> 10, o = idx & 1023;
  cw2T[idx] = cw2[o * 128 + c];
}

// ---------------- Kernel 0b: pack pts -> {x,y,z,|p|^2} float4 ----------------
__global__ __launch_bounds__(256)
void k_pack(const float* __restrict__ pts, float4* __restrict__ pts4) {
  int i = blockIdx.x * 256 + threadIdx.x;     // over NBATCH*NPTS
  float x = pts[3 * i], y = pts[3 * i + 1], z = pts[3 * i + 2];
  pts4[i] = make_float4(x, y, z, x * x + y * y + z * z);
}

// ---------------- Kernel 1: exact 16-NN + covariance features ----------------
// 512 threads = 128 queries x 4 candidate-segments (seg = t>>7, 1024 cands
// each). Candidates stream from global pts4 via wave-uniform (scalarized)
// loads — off the LDS pipe, 8-deep prefetch. Per-thread sorted top-16 in
// registers + LDS append buffer with bitonic merge. Cross-segment 16+16
// bitonic merges (td preferred on ties => earlier index wins) give the exact
// global top-16. 8 waves/CU (vs 2 before).
__global__ __launch_bounds__(512)
void k_knn(const float4* __restrict__ pts4, int* __restrict__ idxo,
           float* __restrict__ x0) {
  __shared__ float4 sp[NPTS];                 // 64 KB (query load + cov gather)
  __shared__ float bufd[16][512];             // 32 KB
  __shared__ unsigned short bufi[16][512];    // 16 KB

  const int b = blockIdx.x >> 5;              // /32 chunks of 128 queries
  const int ch = blockIdx.x & 31;
  const float4* pb4 = pts4 + (size_t)b * NPTS;
  for (int i = threadIdx.x; i < NPTS; i += 512) sp[i] = pb4[i];
  __syncthreads();

  const int t = threadIdx.x;
  const int tq = t & 127;
  const int seg = __builtin_amdgcn_readfirstlane(t >> 7);  // wave-uniform
  const int q = ch * 128 + tq;
  const float4 qp = sp[q];
  const float qs = qp.w;

  float td[16];
  int ti[16];
#pragma unroll
  for (int j = 0; j < 16; j++) { td[j] = 3.0e38f; ti[j] = 0; }
  float worst = 3.0e38f;
  int cnt = 0;

  auto merge = [&]() {
    float bd[16];
    int bi[16];
#pragma unroll
    for (int j = 0; j < 16; j++) {
      bool v = j < cnt;
      float dv = bufd[j][t];
      int iv = (int)bufi[j][t];
      bd[j] = v ? dv : 3.0e38f;
      bi[j] = v ? iv : 0;
    }
    cnt = 0;
    // bitonic sort bd ascending (all indices compile-time)
#pragma unroll
    for (int k = 2; k <= 16; k <<= 1) {
#pragma unroll
      for (int j = k >> 1; j > 0; j >>= 1) {
#pragma unroll
        for (int i = 0; i < 16; i++) {
          int l = i ^ j;
          if (l > i) {
            bool dir = ((i & k) == 0);
            bool sw = dir ? (bd[i] > bd[l]) : (bd[i] < bd[l]);
            float fd = sw ? bd[l] : bd[i];
            float fl = sw ? bd[i] : bd[l];
            int gd = sw ? bi[l] : bi[i];
            int gl = sw ? bi[i] : bi[l];
            bd[i] = fd; bd[l] = fl; bi[i] = gd; bi[l] = gl;
          }
        }
      }
    }
    // cross: keep 16 smallest of {td (asc), bd (asc)}; td wins ties
#pragma unroll
    for (int i = 0; i < 16; i++) {
      int l = 15 - i;
      bool sw = bd[l] < td[i];
      td[i] = sw ? bd[l] : td[i];
      ti[i] = sw ? bi[l] : ti[i];
    }
    // bitonic clean -> ascending
#pragma unroll
    for (int j = 8; j > 0; j >>= 1) {
#pragma unroll
      for (int i = 0; i < 16; i++) {
        int l = i ^ j;
        if (l > i) {
          bool sw = td[i] > td[l];
          float fd = sw ? td[l] : td[i];
          float fl = sw ? td[i] : td[l];
          int gd = sw ? ti[l] : ti[i];
          int gl = sw ? ti[i] : ti[l];
          td[i] = fd; td[l] = fl; ti[i] = gd; ti[l] = gl;
        }
      }
    }
    worst = td[15];
  };

  const float4* ps = pb4 + seg * 1024;        // wave-uniform base
  const int base = seg * 1024;
  for (int i0 = 0; i0 < 1024; i0 += 8) {
    float4 c[8];
#pragma unroll
    for (int u = 0; u < 8; u++) c[u] = ps[i0 + u];   // uniform addr -> scalarized
    float d[8];
#pragma unroll
    for (int u = 0; u < 8; u++)
      d[u] = (qs + c[u].w) - 2.0f * (qp.x * c[u].x + qp.y * c[u].y + qp.z * c[u].z);
#pragma unroll
    for (int u = 0; u < 8; u++) {
      if (d[u] < worst) {               // strict <: earlier index wins ties
        bufd[cnt][t] = d[u];
        bufi[cnt][t] = (unsigned short)(base + i0 + u);
        cnt++;
      }
      if (u == 3 && __any(cnt >= 13)) merge();   // enter<=12, +4 -> cnt<=16
    }
    if (__any(cnt >= 13)) merge();
  }
  if (__any(cnt > 0)) merge();

  // publish per-segment sorted lists, then seg0 merges 4 -> 1
#pragma unroll
  for (int j = 0; j < 16; j++) { bufd[j][t] = td[j]; bufi[j][t] = (unsigned short)ti[j]; }
  __syncthreads();
  if (t < 128) {
#pragma unroll
    for (int s = 1; s < 4; s++) {
      float bd[16];
      int bi[16];
#pragma unroll
      for (int j = 0; j < 16; j++) {
        bd[j] = bufd[j][t + 128 * s];
        bi[j] = (int)bufi[j][t + 128 * s];
      }
#pragma unroll
      for (int i = 0; i < 16; i++) {
        int l = 15 - i;
        bool sw = bd[l] < td[i];      // td (earlier segs) wins ties
        td[i] = sw ? bd[l] : td[i];
        ti[i] = sw ? bi[l] : ti[i];
      }
#pragma unroll
      for (int j = 8; j > 0; j >>= 1) {
#pragma unroll
        for (int i = 0; i < 16; i++) {
          int l = i ^ j;
          if (l > i) {
            bool sw2 = td[i] > td[l];
            float fd = sw2 ? td[l] : td[i];
            float fl = sw2 ? td[i] : td[l];
            int gd = sw2 ? ti[l] : ti[i];
            int gl = sw2 ? ti[i] : ti[l];
            td[i] = fd; td[l] = fl; ti[i] = gd; ti[l] = gl;
          }
        }
      }
    }

    // covariance of mean-centered neighbors
    float nx[16], ny[16], nz[16];
    float mx = 0.f, my = 0.f, mz = 0.f;
#pragma unroll
    for (int k = 0; k < 16; k++) {
      float4 c = sp[ti[k]];
      nx[k] = c.x; ny[k] = c.y; nz[k] = c.z;
      mx += c.x; my += c.y; mz += c.z;
    }
    mx *= 0.0625f; my *= 0.0625f; mz *= 0.0625f;
    float c00 = 0, c01 = 0, c02 = 0, c11 = 0, c12 = 0, c22 = 0;
#pragma unroll
    for (int k = 0; k < 16; k++) {
      float dx = nx[k] - mx, dy = ny[k] - my, dz = nz[k] - mz;
      c00 += dx * dx; c01 += dx * dy; c02 += dx * dz;
      c11 += dy * dy; c12 += dy * dz; c22 += dz * dz;
    }
    size_t row = (size_t)b * NPTS + q;
    float* xo = x0 + row * 12;
    xo[0] = qp.x; xo[1] = qp.y; xo[2] = qp.z;
    xo[3] = c00;  xo[4] = c01;  xo[5] = c02;
    xo[6] = c01;  xo[7] = c11;  xo[8] = c12;
    xo[9] = c02;  xo[10] = c12; xo[11] = c22;
    int* io = idxo + row * 16;
#pragma unroll
    for (int k = 0; k < 16; k++) io[k] = ti[k];
  }
}

// ---------------- Kernel 2: MLP1 12->64->64->64 (relu each) ------------------
__global__ __launch_bounds__(128)
void k_mlp1(const float* __restrict__ x0,
            const float* __restrict__ w1, const float* __restrict__ b1,
            const float* __restrict__ w2, const float* __restrict__ b2,
            const float* __restrict__ w3, const float* __restrict__ b3,
            float* __restrict__ h3o) {
  __shared__ float s1[64 * 12], s2[64 * 64], s3[64 * 64];
  __shared__ float sb1[64], sb2[64], sb3[64];
  for (int i = threadIdx.x; i < 64 * 12; i += 128) s1[i] = w1[i];
  for (int i = threadIdx.x; i < 64 * 64; i += 128) { s2[i] = w2[i]; s3[i] = w3[i]; }
  if (threadIdx.x < 64) {
    sb1[threadIdx.x] = b1[threadIdx.x];
    sb2[threadIdx.x] = b2[threadIdx.x];
    sb3[threadIdx.x] = b3[threadIdx.x];
  }
  __syncthreads();

  size_t p = (size_t)blockIdx.x * 128 + threadIdx.x;
  const float4* xv = (const float4*)(x0 + p * 12);
  float4 xa = xv[0], xb = xv[1], xc = xv[2];

  float h[64];
#pragma unroll
  for (int o = 0; o < 64; o++) {
    const float4* wr = (const float4*)(s1 + o * 12);
    float a = sb1[o] + dot4(wr[0], xa) + dot4(wr[1], xb) + dot4(wr[2], xc);
    h[o] = fmaxf(a, 0.f);
  }
  float g[64];
#pragma unroll
  for (int o = 0; o < 64; o++) {
    float a = sb2[o];
    const float4* wr = (const float4*)(s2 + o * 64);
#pragma unroll
    for (int c4 = 0; c4 < 16; c4++) {
      float4 w = wr[c4];
      a += w.x * h[4 * c4] + w.y * h[4 * c4 + 1] + w.z * h[4 * c4 + 2] + w.w * h[4 * c4 + 3];
    }
    g[o] = fmaxf(a, 0.f);
  }
  float* out = h3o + p * 64;
  for (int o = 0; o < 64; o++) {
    float a = sb3[o];
    const float4* wr = (const float4*)(s3 + o * 64);
#pragma unroll
    for (int c4 = 0; c4 < 16; c4++) {
      float4 w = wr[c4];
      a += w.x * g[4 * c4] + w.y * g[4 * c4 + 1] + w.z * g[4 * c4 + 2] + w.w * g[4 * c4 + 3];
    }
    out[o] = fmaxf(a, 0.f);
  }
}

// -------- Kernel 3: maxpool(h3,idx) -> lw1 (lin) -> relu(cw1) -> z[...,128] --
__global__ __launch_bounds__(128)
void k_graph1(const float* __restrict__ h3, const int* __restrict__ idx,
              const float* __restrict__ lw1, const float* __restrict__ lb1,
              const float* __restrict__ cw1, const float* __restrict__ cb1,
              float* __restrict__ z) {
  __shared__ float sl[64 * 64], sc[128 * 64];
  __shared__ float sbl[64], sbc[128];
  for (int i = threadIdx.x; i < 64 * 64; i += 128) sl[i] = lw1[i];
  for (int i = threadIdx.x; i < 128 * 64; i += 128) sc[i] = cw1[i];
  if (threadIdx.x < 64) sbl[threadIdx.x] = lb1[threadIdx.x];
  if (threadIdx.x < 128) sbc[threadIdx.x] = cb1[threadIdx.x];
  __syncthreads();

  size_t p = (size_t)blockIdx.x * 128 + threadIdx.x;
  int b = (int)(p >> 12);
  const int* ip = idx + p * 16;

  float m[64];
#pragma unroll
  for (int c = 0; c < 64; c++) m[c] = -3.0e38f;
  for (int k = 0; k < 16; k++) {
    const float4* nb = (const float4*)(h3 + (((size_t)b << 12) + ip[k]) * 64);
#pragma unroll
    for (int c4 = 0; c4 < 16; c4++) {
      float4 v = nb[c4];
      m[4 * c4]     = fmaxf(m[4 * c4], v.x);
      m[4 * c4 + 1] = fmaxf(m[4 * c4 + 1], v.y);
      m[4 * c4 + 2] = fmaxf(m[4 * c4 + 2], v.z);
      m[4 * c4 + 3] = fmaxf(m[4 * c4 + 3], v.w);
    }
  }
  float y[64];
#pragma unroll
  for (int o = 0; o < 64; o++) {
    float a = sbl[o];
    const float4* wr = (const float4*)(sl + o * 64);
#pragma unroll
    for (int c4 = 0; c4 < 16; c4++) {
      float4 w = wr[c4];
      a += w.x * m[4 * c4] + w.y * m[4 * c4 + 1] + w.z * m[4 * c4 + 2] + w.w * m[4 * c4 + 3];
    }
    y[o] = a;   // no relu on lw1
  }
  float* zo = z + p * 128;
  for (int o = 0; o < 128; o++) {
    float a = sbc[o];
    const float4* wr = (const float4*)(sc + o * 64);
#pragma unroll
    for (int c4 = 0; c4 < 16; c4++) {
      float4 w = wr[c4];
      a += w.x * y[4 * c4] + w.y * y[4 * c4 + 1] + w.z * y[4 * c4 + 2] + w.w * y[4 * c4 + 3];
    }
    zo[o] = fmaxf(a, 0.f);
  }
}

// ------ Kernel 4: maxpool(z,idx) -> lw2 -> cw2 -> global max (atomic) --------
// block = 64 points of one batch. Phase C uses transposed cw2T (coalesced).
__global__ __launch_bounds__(256)
void k_graph2(const float* __restrict__ z, const int* __restrict__ idx,
              const float* __restrict__ lw2, const float* __restrict__ lb2,
              const float* __restrict__ cw2T, const float* __restrict__ cb2,
              unsigned* __restrict__ gacc) {
  __shared__ float smT[128][64];   // transposed: [channel][point]  32 KB
  __shared__ float st[64][STP];    // [point][channel], padded      33 KB

  const int b = blockIdx.x >> 6;
  const int pbase = (blockIdx.x & 63) * 64;
  const int t = threadIdx.x;

  // Phase A: neighbor maxpool of z -> smT
  {
    const int pl = t & 63, cg = t >> 6;
    size_t p = (size_t)b * NPTS + pbase + pl;
    const int* ip = idx + p * 16;
    float mv[32];
#pragma unroll
    for (int c = 0; c < 32; c++) mv[c] = -3.0e38f;
    for (int k = 0; k < 16; k++) {
      const float4* nb = (const float4*)(z + ((size_t)b * NPTS + ip[k]) * 128 + cg * 32);
#pragma unroll
      for (int c4 = 0; c4 < 8; c4++) {
        float4 v = nb[c4];
        mv[4 * c4]     = fmaxf(mv[4 * c4], v.x);
        mv[4 * c4 + 1] = fmaxf(mv[4 * c4 + 1], v.y);
        mv[4 * c4 + 2] = fmaxf(mv[4 * c4 + 2], v.z);
        mv[4 * c4 + 3] = fmaxf(mv[4 * c4 + 3], v.w);
      }
    }
#pragma unroll
    for (int c = 0; c < 32; c++) smT[cg * 32 + c][pl] = mv[c];
  }
  __syncthreads();

  // Phase B: st[p][o] = lb2[o] + sum_c lw2[o][c]*m[p][c]  (float4 writes)
  {
    const int pl = t & 63, og = t >> 6;
    float acc[32];
#pragma unroll
    for (int oi = 0; oi < 32; oi++) acc[oi] = lb2[og * 32 + oi];
    for (int cb = 0; cb < 4; cb++) {
      float mr[32];
#pragma unroll
      for (int j = 0; j < 32; j++) mr[j] = smT[cb * 32 + j][pl];
#pragma unroll
      for (int oi = 0; oi < 32; oi++) {
        const float4* wr = (const float4*)(lw2 + (size_t)(og * 32 + oi) * 128 + cb * 32);
#pragma unroll
        for (int j4 = 0; j4 < 8; j4++) {
          float4 w = wr[j4];
          acc[oi] += w.x * mr[4 * j4] + w.y * mr[4 * j4 + 1] + w.z * mr[4 * j4 + 2] + w.w * mr[4 * j4 + 3];
        }
      }
    }
#pragma unroll
    for (int oi4 = 0; oi4 < 8; oi4++)
      *(float4*)&st[pl][og * 32 + oi4 * 4] =
          make_float4(acc[4 * oi4], acc[4 * oi4 + 1], acc[4 * oi4 + 2], acc[4 * oi4 + 3]);
  }
  __syncthreads();

  // Phase C: u[o] = cb2[o] + cw2T[:,o].st[p]; max over 64 points; atomic max
  // cw2T[c][o]: lane t reads float4 at col t*4 -> fully coalesced.
  {
    float bias[4], best[4];
#pragma unroll
    for (int oi = 0; oi < 4; oi++) {
      bias[oi] = cb2[t * 4 + oi];
      best[oi] = -3.0e38f;
    }
    for (int p8 = 0; p8 < 64; p8 += 8) {
      float acc[4][8];
#pragma unroll
      for (int oi = 0; oi < 4; oi++)
#pragma unroll
        for (int pp = 0; pp < 8; pp++) acc[oi][pp] = bias[oi];
      for (int c4 = 0; c4 < 32; c4++) {
        float4 sv[8];
#pragma unroll
        for (int pp = 0; pp < 8; pp++) sv[pp] = *(const float4*)&st[p8 + pp][c4 * 4];
        float4 w0 = *(const float4*)&cw2T[(size_t)(c4 * 4 + 0) * 1024 + t * 4];
        float4 w1 = *(const float4*)&cw2T[(size_t)(c4 * 4 + 1) * 1024 + t * 4];
        float4 w2 = *(const float4*)&cw2T[(size_t)(c4 * 4 + 2) * 1024 + t * 4];
        float4 w3 = *(const float4*)&cw2T[(size_t)(c4 * 4 + 3) * 1024 + t * 4];
#pragma unroll
        for (int pp = 0; pp < 8; pp++) {
          float4 s = sv[pp];
          acc[0][pp] += w0.x * s.x + w1.x * s.y + w2.x * s.z + w3.x * s.w;
          acc[1][pp] += w0.y * s.x + w1.y * s.y + w2.y * s.z + w3.y * s.w;
          acc[2][pp] += w0.z * s.x + w1.z * s.y + w2.z * s.z + w3.z * s.w;
          acc[3][pp] += w0.w * s.x + w1.w * s.y + w2.w * s.z + w3.w * s.w;
        }
      }
#pragma unroll
      for (int oi = 0; oi < 4; oi++)
#pragma unroll
        for (int pp = 0; pp < 8; pp++) best[oi] = fmaxf(best[oi], acc[oi][pp]);
    }
#pragma unroll
    for (int oi = 0; oi < 4; oi++)
      atomicMax(&gacc[b * 1024 + t * 4 + oi], fenc(best[oi]));
  }
}

// ---------------- Kernel 5: head MLP 1024 -> 512(relu) -> 512 ----------------
__global__ __launch_bounds__(512)
void k_head(const unsigned* __restrict__ gacc,
            const float* __restrict__ mw1, const float* __restrict__ mb1,
            const float* __restrict__ mw2, const float* __restrict__ mb2,
            float* __restrict__ out) {
  __shared__ float g[1024];
  __shared__ float h[512];
  const int b = blockIdx.x, t = threadIdx.x;
  for (int i = t; i < 1024; i += 512) g[i] = fdec(gacc[b * 1024 + i]);
  __syncthreads();
  float a = mb1[t];
  const float4* wr = (const float4*)(mw1 + (size_t)t * 1024);
  const float4* gv = (const float4*)g;
#pragma unroll 8
  for (int c4 = 0; c4 < 256; c4++) a += dot4(wr[c4], gv[c4]);
  h[t] = fmaxf(a, 0.f);
  __syncthreads();
  float a2 = mb2[t];
  const float4* wr2 = (const float4*)(mw2 + (size_t)t * 512);
  const float4* hv = (const float4*)h;
#pragma unroll 8
  for (int c4 = 0; c4 < 128; c4++) a2 += dot4(wr2[c4], hv[c4]);
  out[(size_t)b * 512 + t] = a2;
}

extern "C" void kernel_launch(void* const* d_in, const int* in_sizes, int n_in,
                              void* d_out, int out_size, void* d_ws, size_t ws_size,
                              hipStream_t stream) {
  const float* pts = (const float*)d_in[0];
  const float* w1  = (const float*)d_in[1];
  const float* b1  = (const float*)d_in[2];
  const float* w2  = (const float*)d_in[3];
  const float* b2  = (const float*)d_in[4];
  const float* w3  = (const float*)d_in[5];
  const float* b3  = (const float*)d_in[6];
  const float* lw1 = (const float*)d_in[7];
  const float* lb1 = (const float*)d_in[8];
  const float* cw1 = (const float*)d_in[9];
  const float* cb1 = (const float*)d_in[10];
  const float* lw2 = (const float*)d_in[11];
  const float* lb2 = (const float*)d_in[12];
  const float* cw2 = (const float*)d_in[13];
  const float* cb2 = (const float*)d_in[14];
  const float* mw1 = (const float*)d_in[15];
  const float* mb1 = (const float*)d_in[16];
  const float* mw2 = (const float*)d_in[17];
  const float* mb2 = (const float*)d_in[18];

  char* ws = (char*)d_ws;
  int*      idx  = (int*)(ws);                                    // 2 MB
  float*    x0   = (float*)(ws + 2097152);                        // 1.5 MB
  float*    h3   = (float*)(ws + 2097152 + 1572864);              // 8 MB
  float*    z    = (float*)(ws + 2097152 + 1572864 + 8388608);    // 16 MB
  unsigned* gacc = (unsigned*)(ws + 28835840);                    // 32 KB
  float*    cw2T = (float*)(ws + 28835840 + 32768);               // 512 KB
  float4*   pts4 = (float4*)(ws + 28835840 + 32768 + 524288);     // 512 KB

  hipMemsetAsync(gacc, 0, NBATCH * 1024 * sizeof(unsigned), stream);
  k_tr<<<512, 256, 0, stream>>>(cw2, cw2T);
  k_pack<<<(NBATCH * NPTS) / 256, 256, 0, stream>>>(pts, pts4);
  k_knn<<<NBATCH * (NPTS / 128), 512, 0, stream>>>(pts4, idx, x0);
  k_mlp1<<<(NBATCH * NPTS) / 128, 128, 0, stream>>>(x0, w1, b1, w2, b2, w3, b3, h3);
  k_graph1<<<(NBATCH * NPTS) / 128, 128, 0, stream>>>(h3, idx, lw1, lb1, cw1, cb1, z);
  k_graph2<<<NBATCH * (NPTS / 64), 256, 0, stream>>>(z, idx, lw2, lb2, cw2T, cb2, gacc);
  k_head<<<NBATCH, 512, 0, stream>>>(gacc, mw1, mb1, mw2, mb2, (float*)d_out);
}